// Round 1
// baseline (1827.104 us; speedup 1.0000x reference)
//
#include <hip/hip_runtime.h>
#include <math.h>

// Problem constants (match reference)
constexpr int N  = 50000;   // nodes
constexpr int NE = 625000;  // edges
constexpr int F  = 128;     // feature dim (F_IN == HID)
constexpr int NG = 128;     // graphs
constexpr int NC = 10;      // classes

// ---------------- CSR build ----------------

__global__ void k_hist(const int* __restrict__ dst, int* __restrict__ deg, int ne) {
    int e = blockIdx.x * blockDim.x + threadIdx.x;
    if (e < ne) atomicAdd(&deg[dst[e]], 1);
}

__global__ void k_scan1(const int* __restrict__ deg, int* __restrict__ excl,
                        int* __restrict__ bsum, int n) {
    __shared__ int s[256];
    int t = threadIdx.x, i = blockIdx.x * 256 + t;
    int v = (i < n) ? deg[i] : 0;
    s[t] = v; __syncthreads();
    for (int d = 1; d < 256; d <<= 1) {
        int u = (t >= d) ? s[t - d] : 0;
        __syncthreads();
        s[t] += u;
        __syncthreads();
    }
    if (i < n) excl[i] = s[t] - v;          // exclusive within block
    if (t == 255) bsum[blockIdx.x] = s[255]; // block total
}

__global__ void k_scan2(const int* __restrict__ bsum, int* __restrict__ boff, int nb) {
    __shared__ int s[256];
    int t = threadIdx.x;
    int v = (t < nb) ? bsum[t] : 0;
    s[t] = v; __syncthreads();
    for (int d = 1; d < 256; d <<= 1) {
        int u = (t >= d) ? s[t - d] : 0;
        __syncthreads();
        s[t] += u;
        __syncthreads();
    }
    if (t < nb) boff[t] = s[t] - v;
}

__global__ void k_scan3(int* __restrict__ indptr, int* __restrict__ cursor,
                        const int* __restrict__ boff, int n, int ne) {
    int i = blockIdx.x * 256 + threadIdx.x;
    if (i < n) {
        int val = indptr[i] + boff[blockIdx.x];
        indptr[i] = val;
        cursor[i] = val;
    }
    if (i == 0) indptr[n] = ne;
}

__global__ void k_fill(const int* __restrict__ src, const int* __restrict__ dst,
                       int* __restrict__ cursor, int* __restrict__ csr, int ne) {
    int e = blockIdx.x * blockDim.x + threadIdx.x;
    if (e < ne) {
        int pos = atomicAdd(&cursor[dst[e]], 1);
        csr[pos] = src[e];
    }
}

// ---------------- aggregation: agg[v] = sum_{e: dst=v} h[src[e]] ----------------

__global__ __launch_bounds__(256) void k_agg(const float* __restrict__ h,
                                             const int* __restrict__ indptr,
                                             const int* __restrict__ csr,
                                             float* __restrict__ agg, int nnodes) {
    int wave = threadIdx.x >> 6;
    int lane = threadIdx.x & 63;
    int v = blockIdx.x * 4 + wave;
    if (v >= nnodes) return;
    int e0 = indptr[v], e1 = indptr[v + 1];
    float2 acc = make_float2(0.f, 0.f);
    for (int e = e0; e < e1; ++e) {
        int s = csr[e];
        float2 t = *(const float2*)(h + (size_t)s * F + lane * 2);
        acc.x += t.x; acc.y += t.y;
    }
    *(float2*)(agg + (size_t)v * F + lane * 2) = acc;
}

// ---------------- fused conv: hout = relu(agg@Wr + br + hin@Ws) ----------------

__global__ __launch_bounds__(256) void k_conv(const float* __restrict__ agg,
                                              const float* __restrict__ hin,
                                              const float* __restrict__ Wr,
                                              const float* __restrict__ br,
                                              const float* __restrict__ Ws,
                                              float* __restrict__ hout, int nrows) {
    __shared__ float sA[32][132];  // pad 132: conflict-free broadcast reads
    __shared__ float sH[32][132];
    const int tid = threadIdx.x;
    const int row0 = blockIdx.x * 32;

    for (int i = tid; i < 32 * 32; i += 256) {
        int r = i >> 5, c4 = (i & 31) * 4;
        int row = row0 + r;
        float4 va = make_float4(0, 0, 0, 0), vh = va;
        if (row < nrows) {
            va = *(const float4*)(agg + (size_t)row * F + c4);
            vh = *(const float4*)(hin + (size_t)row * F + c4);
        }
        *(float4*)(&sA[r][c4]) = va;
        *(float4*)(&sH[r][c4]) = vh;
    }
    __syncthreads();

    const int r  = tid >> 3;        // 0..31 rows
    const int c0 = (tid & 7) * 16;  // 16 consecutive cols
    float acc[16];
#pragma unroll
    for (int j = 0; j < 16; ++j) acc[j] = br[c0 + j];

    const float* wr = Wr + c0;
    const float* wsp = Ws + c0;
#pragma unroll 4
    for (int k = 0; k < 128; ++k) {
        float a = sA[r][k];
        float b = sH[r][k];
        const float4* w4 = (const float4*)(wr + (size_t)k * F);
        const float4* s4 = (const float4*)(wsp + (size_t)k * F);
#pragma unroll
        for (int q = 0; q < 4; ++q) {
            float4 w = w4[q], s = s4[q];
            acc[q * 4 + 0] += a * w.x + b * s.x;
            acc[q * 4 + 1] += a * w.y + b * s.y;
            acc[q * 4 + 2] += a * w.z + b * s.z;
            acc[q * 4 + 3] += a * w.w + b * s.w;
        }
    }

    int row = row0 + r;
    if (row < nrows) {
#pragma unroll
        for (int q = 0; q < 4; ++q) {
            float4 o;
            o.x = fmaxf(acc[q * 4 + 0], 0.f);
            o.y = fmaxf(acc[q * 4 + 1], 0.f);
            o.z = fmaxf(acc[q * 4 + 2], 0.f);
            o.w = fmaxf(acc[q * 4 + 3], 0.f);
            *(float4*)(hout + (size_t)row * F + c0 + q * 4) = o;
        }
    }
}

// ---------------- pooling ----------------

__global__ void k_gstart(const int* __restrict__ batch, int* __restrict__ gstart,
                         int n, int ng) {
    int g = threadIdx.x;
    if (g > ng) return;
    if (g == ng) { gstart[ng] = n; return; }
    int lo = 0, hi = n;
    while (lo < hi) {
        int mid = (lo + hi) >> 1;
        if (batch[mid] < g) lo = mid + 1; else hi = mid;
    }
    gstart[g] = lo;
}

__global__ __launch_bounds__(128) void k_pool(const float* __restrict__ h,
                                              const int* __restrict__ gstart,
                                              float* __restrict__ gacc) {
    int g = blockIdx.x, f = threadIdx.x;
    int s = gstart[g], e = gstart[g + 1];
    float mx = -INFINITY, sm = 0.f;
    for (int v = s; v < e; ++v) {
        float val = h[(size_t)v * F + f];
        mx = fmaxf(mx, val);
        sm += val;
    }
    int cnt = e - s;
    float mean = (cnt > 0) ? sm / (float)cnt : 0.f;
    if (cnt == 0) mx = 0.f;
    gacc[g * 256 + f]       += mx;
    gacc[g * 256 + 128 + f] += mean;
}

// ---------------- MLP head + log_softmax ----------------

__global__ __launch_bounds__(256) void k_mlp(const float* __restrict__ gacc,
                                             const float* __restrict__ L1w, const float* __restrict__ L1b,
                                             const float* __restrict__ L2w, const float* __restrict__ L2b,
                                             const float* __restrict__ L3w, const float* __restrict__ L3b,
                                             float* __restrict__ out) {
    __shared__ float gv[256], o1[128], o2[64], o3[16];
    int g = blockIdx.x, t = threadIdx.x;
    gv[t] = gacc[g * 256 + t];
    __syncthreads();
    if (t < 128) {
        float a = L1b[t];
        for (int k = 0; k < 256; ++k) a += gv[k] * L1w[k * 128 + t];
        o1[t] = fmaxf(a, 0.f);
    }
    __syncthreads();
    if (t < 64) {
        float a = L2b[t];
        for (int k = 0; k < 128; ++k) a += o1[k] * L2w[k * 64 + t];
        o2[t] = fmaxf(a, 0.f);
    }
    __syncthreads();
    if (t < NC) {
        float a = L3b[t];
        for (int k = 0; k < 64; ++k) a += o2[k] * L3w[k * NC + t];
        o3[t] = a;
    }
    __syncthreads();
    if (t < NC) {
        float m = o3[0];
        for (int i = 1; i < NC; ++i) m = fmaxf(m, o3[i]);
        float s = 0.f;
        for (int i = 0; i < NC; ++i) s += expf(o3[i] - m);
        out[g * NC + t] = o3[t] - m - logf(s);
    }
}

// ---------------- host ----------------

extern "C" void kernel_launch(void* const* d_in, const int* in_sizes, int n_in,
                              void* d_out, int out_size, void* d_ws, size_t ws_size,
                              hipStream_t stream) {
    const float* x     = (const float*)d_in[0];
    const int*   ei    = (const int*)d_in[1];   // [2, NE]
    const int*   batch = (const int*)d_in[2];
    const float* W1r = (const float*)d_in[3];
    const float* b1  = (const float*)d_in[4];
    const float* W1s = (const float*)d_in[5];
    const float* W2r = (const float*)d_in[6];
    const float* b2  = (const float*)d_in[7];
    const float* W2s = (const float*)d_in[8];
    const float* W3r = (const float*)d_in[9];
    const float* b3  = (const float*)d_in[10];
    const float* W3s = (const float*)d_in[11];
    const float* L1w = (const float*)d_in[12];
    const float* L1b = (const float*)d_in[13];
    const float* L2w = (const float*)d_in[14];
    const float* L2b = (const float*)d_in[15];
    const float* L3w = (const float*)d_in[16];
    const float* L3b = (const float*)d_in[17];
    float* out = (float*)d_out;

    char* ws = (char*)d_ws;
    const size_t SZ_H = (size_t)N * F * sizeof(float);  // 25.6 MB
    float* agg    = (float*)(ws);
    float* hA     = (float*)(ws + SZ_H);
    float* hB     = (float*)(ws + 2 * SZ_H);
    size_t off    = 3 * SZ_H;
    int* indptr   = (int*)(ws + off); off += 200256;   // N+1 ints
    int* cursor   = (int*)(ws + off); off += 200256;   // also deg
    int* csr      = (int*)(ws + off); off += 2500096;  // NE ints
    int* bsum     = (int*)(ws + off); off += 1024;
    int* boff     = (int*)(ws + off); off += 1024;
    int* gstart   = (int*)(ws + off); off += 1024;     // NG+1 ints
    float* gacc   = (float*)(ws + off); off += 131072; // NG x 256

    const int* src = ei;
    const int* dst = ei + NE;

    // CSR build (reused for all 3 layers)
    hipMemsetAsync(cursor, 0, (size_t)N * sizeof(int), stream);  // deg
    hipMemsetAsync(gacc, 0, (size_t)NG * 256 * sizeof(float), stream);
    k_hist<<<(NE + 255) / 256, 256, 0, stream>>>(dst, cursor, NE);
    const int NB = (N + 255) / 256;  // 196
    k_scan1<<<NB, 256, 0, stream>>>(cursor, indptr, bsum, N);
    k_scan2<<<1, 256, 0, stream>>>(bsum, boff, NB);
    k_scan3<<<NB, 256, 0, stream>>>(indptr, cursor, boff, N, NE);
    k_fill<<<(NE + 255) / 256, 256, 0, stream>>>(src, dst, cursor, csr, NE);
    k_gstart<<<1, 256, 0, stream>>>(batch, gstart, N, NG);

    auto run_layer = [&](const float* hin, const float* Wr, const float* br,
                         const float* Wsp, float* hout) {
        k_agg<<<(N + 3) / 4, 256, 0, stream>>>(hin, indptr, csr, agg, N);
        k_conv<<<(N + 31) / 32, 256, 0, stream>>>(agg, hin, Wr, br, Wsp, hout, N);
        k_pool<<<NG, 128, 0, stream>>>(hout, gstart, gacc);
    };

    run_layer(x,  W1r, b1, W1s, hA);
    run_layer(hA, W2r, b2, W2s, hB);
    run_layer(hB, W3r, b3, W3s, hA);

    k_mlp<<<NG, 256, 0, stream>>>(gacc, L1w, L1b, L2w, L2b, L3w, L3b, out);
}

// Round 2
// 370.288 us; speedup vs baseline: 4.9343x; 4.9343x over previous
//
#include <hip/hip_runtime.h>
#include <math.h>

constexpr int N  = 50000;
constexpr int NE = 625000;
constexpr int F  = 128;
constexpr int NG = 128;
constexpr int NC = 10;

typedef __attribute__((ext_vector_type(4))) float f32x4;
typedef __attribute__((ext_vector_type(8))) short bf16x8;

__device__ __forceinline__ ushort f2bf(float f) {
    unsigned u = __float_as_uint(f);
    u = (u + 0x7FFF + ((u >> 16) & 1)) >> 16;
    return (ushort)u;
}
__device__ __forceinline__ float bf2f(unsigned h) {
    return __uint_as_float(h << 16);
}

// ---------------- conversions ----------------

__global__ __launch_bounds__(256) void k_cvt_x(const float* __restrict__ x,
                                               ushort* __restrict__ xb, int n) {
    int i = (blockIdx.x * 256 + threadIdx.x) * 8;
    if (i >= n) return;
    float4 a = *(const float4*)(x + i);
    float4 b = *(const float4*)(x + i + 4);
    ushort r[8] = {f2bf(a.x), f2bf(a.y), f2bf(a.z), f2bf(a.w),
                   f2bf(b.x), f2bf(b.y), f2bf(b.z), f2bf(b.w)};
    *(uint4*)(xb + i) = *(uint4*)r;
}

// Wt[n][k] = bf16(W[k][n]), W is 128x128
__global__ __launch_bounds__(256) void k_cvt_w(const float* __restrict__ W,
                                               ushort* __restrict__ Wt) {
    int i = blockIdx.x * 256 + threadIdx.x;
    int k = i >> 7, n = i & 127;
    Wt[n * 128 + k] = f2bf(W[k * 128 + n]);
}

// ---------------- CSR build ----------------

__global__ void k_hist(const int* __restrict__ dst, int* __restrict__ deg, int ne) {
    int e = blockIdx.x * blockDim.x + threadIdx.x;
    if (e < ne) atomicAdd(&deg[dst[e]], 1);
}

__global__ void k_scan1(const int* __restrict__ deg, int* __restrict__ excl,
                        int* __restrict__ bsum, int n) {
    __shared__ int s[256];
    int t = threadIdx.x, i = blockIdx.x * 256 + t;
    int v = (i < n) ? deg[i] : 0;
    s[t] = v; __syncthreads();
    for (int d = 1; d < 256; d <<= 1) {
        int u = (t >= d) ? s[t - d] : 0;
        __syncthreads();
        s[t] += u;
        __syncthreads();
    }
    if (i < n) excl[i] = s[t] - v;
    if (t == 255) bsum[blockIdx.x] = s[255];
}

__global__ void k_scan2(const int* __restrict__ bsum, int* __restrict__ boff, int nb) {
    __shared__ int s[256];
    int t = threadIdx.x;
    int v = (t < nb) ? bsum[t] : 0;
    s[t] = v; __syncthreads();
    for (int d = 1; d < 256; d <<= 1) {
        int u = (t >= d) ? s[t - d] : 0;
        __syncthreads();
        s[t] += u;
        __syncthreads();
    }
    if (t < nb) boff[t] = s[t] - v;
}

__global__ void k_scan3(int* __restrict__ indptr, int* __restrict__ cursor,
                        const int* __restrict__ boff, int n, int ne) {
    int i = blockIdx.x * 256 + threadIdx.x;
    if (i < n) {
        int val = indptr[i] + boff[blockIdx.x];
        indptr[i] = val;
        cursor[i] = val;
    }
    if (i == 0) indptr[n] = ne;
}

__global__ void k_fill(const int* __restrict__ src, const int* __restrict__ dst,
                       int* __restrict__ cursor, int* __restrict__ csr, int ne) {
    int e = blockIdx.x * blockDim.x + threadIdx.x;
    if (e < ne) {
        int pos = atomicAdd(&cursor[dst[e]], 1);
        csr[pos] = src[e];
    }
}

// ---------------- aggregation (bf16 rows, fp32 accumulate) ----------------

__global__ __launch_bounds__(256) void k_agg(const ushort* __restrict__ h,
                                             const int* __restrict__ indptr,
                                             const int* __restrict__ csr,
                                             ushort* __restrict__ agg, int nnodes) {
    int wave = threadIdx.x >> 6;
    int lane = threadIdx.x & 63;
    int v = blockIdx.x * 4 + wave;
    if (v >= nnodes) return;
    int e0 = indptr[v], e1 = indptr[v + 1];
    float ax = 0.f, ay = 0.f;
    int e = e0;
    for (; e + 1 < e1; e += 2) {
        int s0 = csr[e], s1 = csr[e + 1];
        unsigned t0 = *(const unsigned*)(h + (size_t)s0 * F + lane * 2);
        unsigned t1 = *(const unsigned*)(h + (size_t)s1 * F + lane * 2);
        ax += bf2f(t0 & 0xffffu) + bf2f(t1 & 0xffffu);
        ay += bf2f(t0 >> 16) + bf2f(t1 >> 16);
    }
    if (e < e1) {
        unsigned t0 = *(const unsigned*)(h + (size_t)csr[e] * F + lane * 2);
        ax += bf2f(t0 & 0xffffu);
        ay += bf2f(t0 >> 16);
    }
    unsigned o = (unsigned)f2bf(ax) | ((unsigned)f2bf(ay) << 16);
    *(unsigned*)(agg + (size_t)v * F + lane * 2) = o;
}

// ---------------- conv: hout = relu(agg@Wr + br + hin@Ws), MFMA bf16 ----------------

#define LDSTR 136  // bf16 elements per LDS row (16B-aligned stride, low conflicts)

__global__ __launch_bounds__(256) void k_conv(const ushort* __restrict__ Abf,
                                              const ushort* __restrict__ Hbf,
                                              const ushort* __restrict__ WrT,
                                              const ushort* __restrict__ WsT,
                                              const float* __restrict__ br,
                                              ushort* __restrict__ hout, int nrows) {
    __shared__ ushort sA[64][LDSTR];
    __shared__ ushort sB[128][LDSTR];
    const int tid = threadIdx.x;
    const int r0 = blockIdx.x * 64;
    const int wv = tid >> 6, lane = tid & 63;
    const int lo16 = lane & 15, hi = lane >> 4;
    const int ncol0 = wv * 32;

    f32x4 acc[4][2];
    {
        float bias0 = br[ncol0 + lo16];
        float bias1 = br[ncol0 + 16 + lo16];
#pragma unroll
        for (int m = 0; m < 4; ++m) {
            acc[m][0] = (f32x4){bias0, bias0, bias0, bias0};
            acc[m][1] = (f32x4){bias1, bias1, bias1, bias1};
        }
    }

#pragma unroll 1
    for (int ph = 0; ph < 2; ++ph) {
        const ushort* Aptr = ph ? Hbf : Abf;
        const ushort* Wptr = ph ? WsT : WrT;
        if (ph) __syncthreads();  // protect LDS reuse

        // stage A: 64 rows x 128 bf16 (1024 uint4 / 4 per thread)
#pragma unroll
        for (int it = 0; it < 4; ++it) {
            int flat = tid + it * 256;
            int row = flat >> 4, c8 = (flat & 15) * 8;
            uint4 v = {0, 0, 0, 0};
            int gr = r0 + row;
            if (gr < nrows) v = *(const uint4*)(Aptr + (size_t)gr * F + c8);
            *(uint4*)(&sA[row][c8]) = v;
        }
        // stage B: 128 rows x 128 bf16 (2048 uint4 / 8 per thread)
#pragma unroll
        for (int it = 0; it < 8; ++it) {
            int flat = tid + it * 256;
            int row = flat >> 4, c8 = (flat & 15) * 8;
            *(uint4*)(&sB[row][c8]) = *(const uint4*)(Wptr + row * F + c8);
        }
        __syncthreads();

#pragma unroll
        for (int ks = 0; ks < 4; ++ks) {
            int k0 = ks * 32 + hi * 8;
            bf16x8 a[4], b[2];
#pragma unroll
            for (int m = 0; m < 4; ++m)
                a[m] = *(const bf16x8*)(&sA[m * 16 + lo16][k0]);
#pragma unroll
            for (int n = 0; n < 2; ++n)
                b[n] = *(const bf16x8*)(&sB[ncol0 + n * 16 + lo16][k0]);
#pragma unroll
            for (int m = 0; m < 4; ++m)
#pragma unroll
                for (int n = 0; n < 2; ++n)
                    acc[m][n] = __builtin_amdgcn_mfma_f32_16x16x32_bf16(
                        a[m], b[n], acc[m][n], 0, 0, 0);
        }
    }

    // epilogue: relu + bf16 store. C/D map: col=lane&15, row=(lane>>4)*4+q
#pragma unroll
    for (int m = 0; m < 4; ++m) {
#pragma unroll
        for (int nt = 0; nt < 2; ++nt) {
            int col = ncol0 + nt * 16 + lo16;
#pragma unroll
            for (int q = 0; q < 4; ++q) {
                int row = r0 + m * 16 + hi * 4 + q;
                if (row < nrows) {
                    float v = fmaxf(acc[m][nt][q], 0.f);
                    hout[(size_t)row * F + col] = f2bf(v);
                }
            }
        }
    }
}

// ---------------- pooling ----------------

__global__ void k_gstart(const int* __restrict__ batch, int* __restrict__ gstart,
                         int n, int ng) {
    int g = threadIdx.x;
    if (g > ng) return;
    if (g == ng) { gstart[ng] = n; return; }
    int lo = 0, hi = n;
    while (lo < hi) {
        int mid = (lo + hi) >> 1;
        if (batch[mid] < g) lo = mid + 1; else hi = mid;
    }
    gstart[g] = lo;
}

__global__ __launch_bounds__(512) void k_pool(const ushort* __restrict__ h,
                                              const int* __restrict__ gstart,
                                              float* __restrict__ gacc) {
    __shared__ float smx[4][128], ssm[4][128];
    int g = blockIdx.x, t = threadIdx.x;
    int f = t & 127, part = t >> 7;
    int s = gstart[g], e = gstart[g + 1];
    float mx = -INFINITY, sm = 0.f;
    for (int v = s + part; v < e; v += 4) {
        float val = bf2f(h[(size_t)v * F + f]);
        mx = fmaxf(mx, val);
        sm += val;
    }
    smx[part][f] = mx; ssm[part][f] = sm;
    __syncthreads();
    if (t < 128) {
        float m = fmaxf(fmaxf(smx[0][f], smx[1][f]), fmaxf(smx[2][f], smx[3][f]));
        float s4 = ssm[0][f] + ssm[1][f] + ssm[2][f] + ssm[3][f];
        int cnt = e - s;
        float mean = (cnt > 0) ? s4 / (float)cnt : 0.f;
        if (cnt == 0) m = 0.f;
        gacc[g * 256 + f]       += m;
        gacc[g * 256 + 128 + f] += mean;
    }
}

// ---------------- MLP head + log_softmax ----------------

__global__ __launch_bounds__(256) void k_mlp(const float* __restrict__ gacc,
                                             const float* __restrict__ L1w, const float* __restrict__ L1b,
                                             const float* __restrict__ L2w, const float* __restrict__ L2b,
                                             const float* __restrict__ L3w, const float* __restrict__ L3b,
                                             float* __restrict__ out) {
    __shared__ float gv[256], o1[128], o2[64], o3[16];
    int g = blockIdx.x, t = threadIdx.x;
    gv[t] = gacc[g * 256 + t];
    __syncthreads();
    if (t < 128) {
        float a = L1b[t];
        for (int k = 0; k < 256; ++k) a += gv[k] * L1w[k * 128 + t];
        o1[t] = fmaxf(a, 0.f);
    }
    __syncthreads();
    if (t < 64) {
        float a = L2b[t];
        for (int k = 0; k < 128; ++k) a += o1[k] * L2w[k * 64 + t];
        o2[t] = fmaxf(a, 0.f);
    }
    __syncthreads();
    if (t < NC) {
        float a = L3b[t];
        for (int k = 0; k < 64; ++k) a += o2[k] * L3w[k * NC + t];
        o3[t] = a;
    }
    __syncthreads();
    if (t < NC) {
        float m = o3[0];
        for (int i = 1; i < NC; ++i) m = fmaxf(m, o3[i]);
        float s = 0.f;
        for (int i = 0; i < NC; ++i) s += expf(o3[i] - m);
        out[g * NC + t] = o3[t] - m - logf(s);
    }
}

// ---------------- host ----------------

extern "C" void kernel_launch(void* const* d_in, const int* in_sizes, int n_in,
                              void* d_out, int out_size, void* d_ws, size_t ws_size,
                              hipStream_t stream) {
    const float* x     = (const float*)d_in[0];
    const int*   ei    = (const int*)d_in[1];
    const int*   batch = (const int*)d_in[2];
    const float* W1r = (const float*)d_in[3];
    const float* b1  = (const float*)d_in[4];
    const float* W1s = (const float*)d_in[5];
    const float* W2r = (const float*)d_in[6];
    const float* b2  = (const float*)d_in[7];
    const float* W2s = (const float*)d_in[8];
    const float* W3r = (const float*)d_in[9];
    const float* b3  = (const float*)d_in[10];
    const float* W3s = (const float*)d_in[11];
    const float* L1w = (const float*)d_in[12];
    const float* L1b = (const float*)d_in[13];
    const float* L2w = (const float*)d_in[14];
    const float* L2b = (const float*)d_in[15];
    const float* L3w = (const float*)d_in[16];
    const float* L3b = (const float*)d_in[17];
    float* out = (float*)d_out;

    char* ws = (char*)d_ws;
    const size_t SZ_HB = (size_t)N * F * sizeof(ushort);  // 12.8 MB
    ushort* x_bf  = (ushort*)(ws);
    ushort* agg_bf= (ushort*)(ws + SZ_HB);
    ushort* hA    = (ushort*)(ws + 2 * SZ_HB);
    ushort* hB    = (ushort*)(ws + 3 * SZ_HB);
    size_t off    = 4 * SZ_HB;
    ushort* Wt[6];
    for (int i = 0; i < 6; ++i) { Wt[i] = (ushort*)(ws + off); off += 128 * 128 * 2; }
    int* indptr   = (int*)(ws + off); off += 200256;
    int* cursor   = (int*)(ws + off); off += 200256;
    int* csr      = (int*)(ws + off); off += 2500096;
    int* bsum     = (int*)(ws + off); off += 1024;
    int* boff     = (int*)(ws + off); off += 1024;
    int* gstart   = (int*)(ws + off); off += 1024;
    float* gacc   = (float*)(ws + off); off += 131072;

    const int* src = ei;
    const int* dst = ei + NE;

    hipMemsetAsync(cursor, 0, (size_t)N * sizeof(int), stream);
    hipMemsetAsync(gacc, 0, (size_t)NG * 256 * sizeof(float), stream);

    // conversions
    k_cvt_x<<<(N * F) / (256 * 8), 256, 0, stream>>>(x, x_bf, N * F);
    k_cvt_w<<<64, 256, 0, stream>>>(W1r, Wt[0]);
    k_cvt_w<<<64, 256, 0, stream>>>(W1s, Wt[1]);
    k_cvt_w<<<64, 256, 0, stream>>>(W2r, Wt[2]);
    k_cvt_w<<<64, 256, 0, stream>>>(W2s, Wt[3]);
    k_cvt_w<<<64, 256, 0, stream>>>(W3r, Wt[4]);
    k_cvt_w<<<64, 256, 0, stream>>>(W3s, Wt[5]);

    // CSR build
    k_hist<<<(NE + 255) / 256, 256, 0, stream>>>(dst, cursor, NE);
    const int NB = (N + 255) / 256;
    k_scan1<<<NB, 256, 0, stream>>>(cursor, indptr, bsum, N);
    k_scan2<<<1, 256, 0, stream>>>(bsum, boff, NB);
    k_scan3<<<NB, 256, 0, stream>>>(indptr, cursor, boff, N, NE);
    k_fill<<<(NE + 255) / 256, 256, 0, stream>>>(src, dst, cursor, csr, NE);
    k_gstart<<<1, 256, 0, stream>>>(batch, gstart, N, NG);

    auto run_layer = [&](const ushort* hin, const ushort* WrT, const float* brr,
                         const ushort* WsT, ushort* hout) {
        k_agg<<<(N + 3) / 4, 256, 0, stream>>>(hin, indptr, csr, agg_bf, N);
        k_conv<<<(N + 63) / 64, 256, 0, stream>>>(agg_bf, hin, WrT, WsT, brr, hout, N);
        k_pool<<<NG, 512, 0, stream>>>(hout, gstart, gacc);
    };

    run_layer(x_bf, Wt[0], b1, Wt[1], hA);
    run_layer(hA,   Wt[2], b2, Wt[3], hB);
    run_layer(hB,   Wt[4], b3, Wt[5], hA);

    k_mlp<<<NG, 256, 0, stream>>>(gacc, L1w, L1b, L2w, L2b, L3w, L3b, out);
}

// Round 3
// 335.253 us; speedup vs baseline: 5.4499x; 1.1045x over previous
//
#include <hip/hip_runtime.h>
#include <math.h>

constexpr int N  = 50000;
constexpr int NE = 625000;
constexpr int F  = 128;
constexpr int NG = 128;
constexpr int NC = 10;

typedef __attribute__((ext_vector_type(4))) float f32x4;
typedef __attribute__((ext_vector_type(8))) short bf16x8;

__device__ __forceinline__ ushort f2bf(float f) {
    unsigned u = __float_as_uint(f);
    u = (u + 0x7FFF + ((u >> 16) & 1)) >> 16;
    return (ushort)u;
}
__device__ __forceinline__ float bf2f(unsigned h) {
    return __uint_as_float(h << 16);
}

// ---------------- conversions ----------------

__global__ __launch_bounds__(256) void k_cvt_x(const float* __restrict__ x,
                                               ushort* __restrict__ xb, int n) {
    int i = (blockIdx.x * 256 + threadIdx.x) * 8;
    if (i >= n) return;
    float4 a = *(const float4*)(x + i);
    float4 b = *(const float4*)(x + i + 4);
    ushort r[8] = {f2bf(a.x), f2bf(a.y), f2bf(a.z), f2bf(a.w),
                   f2bf(b.x), f2bf(b.y), f2bf(b.z), f2bf(b.w)};
    *(uint4*)(xb + i) = *(uint4*)r;
}

// Wt[n][k] = bf16(W[k][n]), W is 128x128
__global__ __launch_bounds__(256) void k_cvt_w(const float* __restrict__ W,
                                               ushort* __restrict__ Wt) {
    int i = blockIdx.x * 256 + threadIdx.x;
    int k = i >> 7, n = i & 127;
    Wt[n * 128 + k] = f2bf(W[k * 128 + n]);
}

// ---------------- CSR build ----------------

__global__ void k_hist(const int* __restrict__ dst, int* __restrict__ deg, int ne) {
    int e = blockIdx.x * blockDim.x + threadIdx.x;
    if (e < ne) atomicAdd(&deg[dst[e]], 1);
}

__global__ void k_scan1(const int* __restrict__ deg, int* __restrict__ excl,
                        int* __restrict__ bsum, int n) {
    __shared__ int s[256];
    int t = threadIdx.x, i = blockIdx.x * 256 + t;
    int v = (i < n) ? deg[i] : 0;
    s[t] = v; __syncthreads();
    for (int d = 1; d < 256; d <<= 1) {
        int u = (t >= d) ? s[t - d] : 0;
        __syncthreads();
        s[t] += u;
        __syncthreads();
    }
    if (i < n) excl[i] = s[t] - v;
    if (t == 255) bsum[blockIdx.x] = s[255];
}

__global__ void k_scan2(const int* __restrict__ bsum, int* __restrict__ boff, int nb) {
    __shared__ int s[256];
    int t = threadIdx.x;
    int v = (t < nb) ? bsum[t] : 0;
    s[t] = v; __syncthreads();
    for (int d = 1; d < 256; d <<= 1) {
        int u = (t >= d) ? s[t - d] : 0;
        __syncthreads();
        s[t] += u;
        __syncthreads();
    }
    if (t < nb) boff[t] = s[t] - v;
}

__global__ void k_scan3(int* __restrict__ indptr, int* __restrict__ cursor,
                        const int* __restrict__ boff, int n, int ne) {
    int i = blockIdx.x * 256 + threadIdx.x;
    if (i < n) {
        int val = indptr[i] + boff[blockIdx.x];
        indptr[i] = val;
        cursor[i] = val;
    }
    if (i == 0) indptr[n] = ne;
}

__global__ void k_fill(const int* __restrict__ src, const int* __restrict__ dst,
                       int* __restrict__ cursor, int* __restrict__ csr, int ne) {
    int e = blockIdx.x * blockDim.x + threadIdx.x;
    if (e < ne) {
        int pos = atomicAdd(&cursor[dst[e]], 1);
        csr[pos] = src[e];
    }
}

// ---------------- aggregation ----------------
// One wave per node. Lane (g = lane>>4, s = lane&15): edge sub-group g loads
// column slice s (8 bf16, uint4). 4 edges in flight per sub-iter, unroll 4
// => up to 16 independent 16B loads per lane batch. Cross-group reduce via
// shfl_xor(16/32), lanes g==0 store the row.

__global__ __launch_bounds__(256) void k_agg(const ushort* __restrict__ h,
                                             const int* __restrict__ indptr,
                                             const int* __restrict__ csr,
                                             ushort* __restrict__ agg, int nnodes) {
    int wave = threadIdx.x >> 6;
    int lane = threadIdx.x & 63;
    int g = lane >> 4;
    int s = lane & 15;
    int v = blockIdx.x * 4 + wave;
    if (v >= nnodes) return;
    int e0 = indptr[v], e1 = indptr[v + 1];
    int deg = e1 - e0;
    float acc[8] = {0.f, 0.f, 0.f, 0.f, 0.f, 0.f, 0.f, 0.f};
    for (int base = 0; base < deg; base += 16) {
#pragma unroll
        for (int u = 0; u < 4; ++u) {
            int e = base + u * 4 + g;
            if (e < deg) {
                int srcn = csr[e0 + e];
                uint4 w = *(const uint4*)(h + (size_t)srcn * F + s * 8);
                acc[0] += bf2f(w.x & 0xffffu); acc[1] += bf2f(w.x >> 16);
                acc[2] += bf2f(w.y & 0xffffu); acc[3] += bf2f(w.y >> 16);
                acc[4] += bf2f(w.z & 0xffffu); acc[5] += bf2f(w.z >> 16);
                acc[6] += bf2f(w.w & 0xffffu); acc[7] += bf2f(w.w >> 16);
            }
        }
    }
#pragma unroll
    for (int i = 0; i < 8; ++i) {
        acc[i] += __shfl_xor(acc[i], 16, 64);
        acc[i] += __shfl_xor(acc[i], 32, 64);
    }
    if (g == 0) {
        ushort r[8];
#pragma unroll
        for (int i = 0; i < 8; ++i) r[i] = f2bf(acc[i]);
        *(uint4*)(agg + (size_t)v * F + s * 8) = *(uint4*)r;
    }
}

// ---------------- conv: hout = relu(agg@Wr + br + hin@Ws), MFMA bf16 ----------------

#define LDSTR 136  // bf16 elements per LDS row (16B-aligned stride, low conflicts)

__global__ __launch_bounds__(256) void k_conv(const ushort* __restrict__ Abf,
                                              const ushort* __restrict__ Hbf,
                                              const ushort* __restrict__ WrT,
                                              const ushort* __restrict__ WsT,
                                              const float* __restrict__ br,
                                              ushort* __restrict__ hout, int nrows) {
    __shared__ ushort sA[64][LDSTR];
    __shared__ ushort sB[128][LDSTR];
    const int tid = threadIdx.x;
    const int r0 = blockIdx.x * 64;
    const int wv = tid >> 6, lane = tid & 63;
    const int lo16 = lane & 15, hi = lane >> 4;
    const int ncol0 = wv * 32;

    f32x4 acc[4][2];
    {
        float bias0 = br[ncol0 + lo16];
        float bias1 = br[ncol0 + 16 + lo16];
#pragma unroll
        for (int m = 0; m < 4; ++m) {
            acc[m][0] = (f32x4){bias0, bias0, bias0, bias0};
            acc[m][1] = (f32x4){bias1, bias1, bias1, bias1};
        }
    }

#pragma unroll 1
    for (int ph = 0; ph < 2; ++ph) {
        const ushort* Aptr = ph ? Hbf : Abf;
        const ushort* Wptr = ph ? WsT : WrT;
        if (ph) __syncthreads();  // protect LDS reuse

#pragma unroll
        for (int it = 0; it < 4; ++it) {
            int flat = tid + it * 256;
            int row = flat >> 4, c8 = (flat & 15) * 8;
            uint4 v = {0, 0, 0, 0};
            int gr = r0 + row;
            if (gr < nrows) v = *(const uint4*)(Aptr + (size_t)gr * F + c8);
            *(uint4*)(&sA[row][c8]) = v;
        }
#pragma unroll
        for (int it = 0; it < 8; ++it) {
            int flat = tid + it * 256;
            int row = flat >> 4, c8 = (flat & 15) * 8;
            *(uint4*)(&sB[row][c8]) = *(const uint4*)(Wptr + row * F + c8);
        }
        __syncthreads();

#pragma unroll
        for (int ks = 0; ks < 4; ++ks) {
            int k0 = ks * 32 + hi * 8;
            bf16x8 a[4], b[2];
#pragma unroll
            for (int m = 0; m < 4; ++m)
                a[m] = *(const bf16x8*)(&sA[m * 16 + lo16][k0]);
#pragma unroll
            for (int n = 0; n < 2; ++n)
                b[n] = *(const bf16x8*)(&sB[ncol0 + n * 16 + lo16][k0]);
#pragma unroll
            for (int m = 0; m < 4; ++m)
#pragma unroll
                for (int n = 0; n < 2; ++n)
                    acc[m][n] = __builtin_amdgcn_mfma_f32_16x16x32_bf16(
                        a[m], b[n], acc[m][n], 0, 0, 0);
        }
    }

    // epilogue: relu + bf16 store. C/D map: col=lane&15, row=(lane>>4)*4+q
#pragma unroll
    for (int m = 0; m < 4; ++m) {
#pragma unroll
        for (int nt = 0; nt < 2; ++nt) {
            int col = ncol0 + nt * 16 + lo16;
#pragma unroll
            for (int q = 0; q < 4; ++q) {
                int row = r0 + m * 16 + hi * 4 + q;
                if (row < nrows) {
                    float v = fmaxf(acc[m][nt][q], 0.f);
                    hout[(size_t)row * F + col] = f2bf(v);
                }
            }
        }
    }
}

// ---------------- pooling ----------------

__global__ void k_gstart(const int* __restrict__ batch, int* __restrict__ gstart,
                         int n, int ng) {
    int g = threadIdx.x;
    if (g > ng) return;
    if (g == ng) { gstart[ng] = n; return; }
    int lo = 0, hi = n;
    while (lo < hi) {
        int mid = (lo + hi) >> 1;
        if (batch[mid] < g) lo = mid + 1; else hi = mid;
    }
    gstart[g] = lo;
}

__global__ __launch_bounds__(512) void k_pool(const ushort* __restrict__ h,
                                              const int* __restrict__ gstart,
                                              float* __restrict__ gacc) {
    __shared__ float smx[4][128], ssm[4][128];
    int g = blockIdx.x, t = threadIdx.x;
    int f = t & 127, part = t >> 7;
    int s = gstart[g], e = gstart[g + 1];
    float mx = -INFINITY, sm = 0.f;
    for (int v = s + part; v < e; v += 4) {
        float val = bf2f(h[(size_t)v * F + f]);
        mx = fmaxf(mx, val);
        sm += val;
    }
    smx[part][f] = mx; ssm[part][f] = sm;
    __syncthreads();
    if (t < 128) {
        float m = fmaxf(fmaxf(smx[0][f], smx[1][f]), fmaxf(smx[2][f], smx[3][f]));
        float s4 = ssm[0][f] + ssm[1][f] + ssm[2][f] + ssm[3][f];
        int cnt = e - s;
        float mean = (cnt > 0) ? s4 / (float)cnt : 0.f;
        if (cnt == 0) m = 0.f;
        gacc[g * 256 + f]       += m;
        gacc[g * 256 + 128 + f] += mean;
    }
}

// ---------------- MLP head + log_softmax ----------------

__global__ __launch_bounds__(256) void k_mlp(const float* __restrict__ gacc,
                                             const float* __restrict__ L1w, const float* __restrict__ L1b,
                                             const float* __restrict__ L2w, const float* __restrict__ L2b,
                                             const float* __restrict__ L3w, const float* __restrict__ L3b,
                                             float* __restrict__ out) {
    __shared__ float gv[256], o1[128], o2[64], o3[16];
    int g = blockIdx.x, t = threadIdx.x;
    gv[t] = gacc[g * 256 + t];
    __syncthreads();
    if (t < 128) {
        float a = L1b[t];
        for (int k = 0; k < 256; ++k) a += gv[k] * L1w[k * 128 + t];
        o1[t] = fmaxf(a, 0.f);
    }
    __syncthreads();
    if (t < 64) {
        float a = L2b[t];
        for (int k = 0; k < 128; ++k) a += o1[k] * L2w[k * 64 + t];
        o2[t] = fmaxf(a, 0.f);
    }
    __syncthreads();
    if (t < NC) {
        float a = L3b[t];
        for (int k = 0; k < 64; ++k) a += o2[k] * L3w[k * NC + t];
        o3[t] = a;
    }
    __syncthreads();
    if (t < NC) {
        float m = o3[0];
        for (int i = 1; i < NC; ++i) m = fmaxf(m, o3[i]);
        float s = 0.f;
        for (int i = 0; i < NC; ++i) s += expf(o3[i] - m);
        out[g * NC + t] = o3[t] - m - logf(s);
    }
}

// ---------------- host ----------------

extern "C" void kernel_launch(void* const* d_in, const int* in_sizes, int n_in,
                              void* d_out, int out_size, void* d_ws, size_t ws_size,
                              hipStream_t stream) {
    const float* x     = (const float*)d_in[0];
    const int*   ei    = (const int*)d_in[1];
    const int*   batch = (const int*)d_in[2];
    const float* W1r = (const float*)d_in[3];
    const float* b1  = (const float*)d_in[4];
    const float* W1s = (const float*)d_in[5];
    const float* W2r = (const float*)d_in[6];
    const float* b2  = (const float*)d_in[7];
    const float* W2s = (const float*)d_in[8];
    const float* W3r = (const float*)d_in[9];
    const float* b3  = (const float*)d_in[10];
    const float* W3s = (const float*)d_in[11];
    const float* L1w = (const float*)d_in[12];
    const float* L1b = (const float*)d_in[13];
    const float* L2w = (const float*)d_in[14];
    const float* L2b = (const float*)d_in[15];
    const float* L3w = (const float*)d_in[16];
    const float* L3b = (const float*)d_in[17];
    float* out = (float*)d_out;

    char* ws = (char*)d_ws;
    const size_t SZ_HB = (size_t)N * F * sizeof(ushort);  // 12.8 MB
    ushort* x_bf  = (ushort*)(ws);
    ushort* agg_bf= (ushort*)(ws + SZ_HB);
    ushort* hA    = (ushort*)(ws + 2 * SZ_HB);
    ushort* hB    = (ushort*)(ws + 3 * SZ_HB);
    size_t off    = 4 * SZ_HB;
    ushort* Wt[6];
    for (int i = 0; i < 6; ++i) { Wt[i] = (ushort*)(ws + off); off += 128 * 128 * 2; }
    int* indptr   = (int*)(ws + off); off += 200256;
    int* cursor   = (int*)(ws + off); off += 200256;
    int* csr      = (int*)(ws + off); off += 2500096;
    int* bsum     = (int*)(ws + off); off += 1024;
    int* boff     = (int*)(ws + off); off += 1024;
    int* gstart   = (int*)(ws + off); off += 1024;
    float* gacc   = (float*)(ws + off); off += 131072;

    const int* src = ei;
    const int* dst = ei + NE;

    hipMemsetAsync(cursor, 0, (size_t)N * sizeof(int), stream);
    hipMemsetAsync(gacc, 0, (size_t)NG * 256 * sizeof(float), stream);

    k_cvt_x<<<(N * F) / (256 * 8), 256, 0, stream>>>(x, x_bf, N * F);
    k_cvt_w<<<64, 256, 0, stream>>>(W1r, Wt[0]);
    k_cvt_w<<<64, 256, 0, stream>>>(W1s, Wt[1]);
    k_cvt_w<<<64, 256, 0, stream>>>(W2r, Wt[2]);
    k_cvt_w<<<64, 256, 0, stream>>>(W2s, Wt[3]);
    k_cvt_w<<<64, 256, 0, stream>>>(W3r, Wt[4]);
    k_cvt_w<<<64, 256, 0, stream>>>(W3s, Wt[5]);

    k_hist<<<(NE + 255) / 256, 256, 0, stream>>>(dst, cursor, NE);
    const int NB = (N + 255) / 256;
    k_scan1<<<NB, 256, 0, stream>>>(cursor, indptr, bsum, N);
    k_scan2<<<1, 256, 0, stream>>>(bsum, boff, NB);
    k_scan3<<<NB, 256, 0, stream>>>(indptr, cursor, boff, N, NE);
    k_fill<<<(NE + 255) / 256, 256, 0, stream>>>(src, dst, cursor, csr, NE);
    k_gstart<<<1, 256, 0, stream>>>(batch, gstart, N, NG);

    auto run_layer = [&](const ushort* hin, const ushort* WrT, const float* brr,
                         const ushort* WsT, ushort* hout) {
        k_agg<<<(N + 3) / 4, 256, 0, stream>>>(hin, indptr, csr, agg_bf, N);
        k_conv<<<(N + 63) / 64, 256, 0, stream>>>(agg_bf, hin, WrT, WsT, brr, hout, N);
        k_pool<<<NG, 512, 0, stream>>>(hout, gstart, gacc);
    };

    run_layer(x_bf, Wt[0], b1, Wt[1], hA);
    run_layer(hA,   Wt[2], b2, Wt[3], hB);
    run_layer(hB,   Wt[4], b3, Wt[5], hA);

    k_mlp<<<NG, 256, 0, stream>>>(gacc, L1w, L1b, L2w, L2b, L3w, L3b, out);
}